// Round 1
// baseline (584.429 us; speedup 1.0000x reference)
//
#include <hip/hip_runtime.h>
#include <hip/hip_bf16.h>
#include <stdint.h>

// MoE: T=4096 tokens, D_MODEL=1024, D_FF=4096, E=8, top-2.
// Sparse grouped-GEMM pipeline, bf16 MFMA compute, fp32 gating.

#define T_TOK 4096
#define DM 1024
#define DF 4096
#define NE 8
#define BM 128
#define BN 128
#define BK 64
#define MAX_TILES 72        // sum ceil(count_e/128) <= 64 + 8
#define PAIR_CAP 9216       // MAX_TILES * 128

typedef __bf16 bf16x8 __attribute__((ext_vector_type(8)));
typedef float f32x4 __attribute__((ext_vector_type(4)));
typedef unsigned short ushort_t;

__device__ __forceinline__ ushort_t f2bf(float f) {
  uint32_t u = __float_as_uint(f);
  u += 0x7FFFu + ((u >> 16) & 1u);   // RNE
  return (ushort_t)(u >> 16);
}

// ---- workspace layout (bytes) ----
#define W1T_OFF 0ull                  // [E][DF][DM] bf16 = 64MiB
#define W2T_OFF 67108864ull           // [E][DM][DF] bf16 = 64MiB
#define XB_OFF  134217728ull          // [T][DM] bf16 = 8MiB
#define H_OFF   142606336ull          // [PAIR_CAP][DF] bf16 = 72MiB
#define RT_OFF  218103808ull          // routing block
// routing sub-offsets (bytes from RT_OFF)
#define RO_COUNTS   0
#define RO_OFFSETS  32
#define RO_CURSORS  64
#define RO_NTILES   96
#define RO_TILE_E   128
#define RO_TILE_S   416
#define RO_TILE_R   704
#define RO_PTOK     1024
#define RO_PW       37888
#define RO_TOPI     74752
#define RO_TOPW     107520
#define RT_BYTES    140288ull
#define WS_NEEDED   (RT_OFF + RT_BYTES)

// ------------------------------------------------------------------
// 1. Gating: one wave per token. fp32 dot products, top-2, softmax.
// ------------------------------------------------------------------
__global__ void gate_kernel(const float* __restrict__ x, const float* __restrict__ gw,
                            int* __restrict__ counts, int* __restrict__ topi,
                            float* __restrict__ topw) {
  int wave = threadIdx.x >> 6;
  int lane = threadIdx.x & 63;
  int t = blockIdx.x * 4 + wave;
  const float* xr = x + (size_t)t * DM;
  float acc[NE];
#pragma unroll
  for (int e = 0; e < NE; ++e) acc[e] = 0.f;
  for (int d = lane; d < DM; d += 64) {
    float xv = xr[d];
    const float* g = gw + (size_t)d * NE;
#pragma unroll
    for (int e = 0; e < NE; ++e) acc[e] += xv * g[e];
  }
#pragma unroll
  for (int off = 32; off > 0; off >>= 1) {
#pragma unroll
    for (int e = 0; e < NE; ++e) acc[e] += __shfl_xor(acc[e], off, 64);
  }
  if (lane == 0) {
    int i0 = 0; float v0 = acc[0];
#pragma unroll
    for (int e = 1; e < NE; ++e) if (acc[e] > v0) { v0 = acc[e]; i0 = e; }
    int i1 = -1; float v1 = -1e30f;
#pragma unroll
    for (int e = 0; e < NE; ++e) if (e != i0 && acc[e] > v1) { v1 = acc[e]; i1 = e; }
    float e1 = expf(v1 - v0);          // <= 1
    float w0 = 1.f / (1.f + e1);
    float w1 = e1 / (1.f + e1);
    topi[t * 2] = i0; topi[t * 2 + 1] = i1;
    topw[t * 2] = w0; topw[t * 2 + 1] = w1;
    atomicAdd(&counts[i0], 1);
    atomicAdd(&counts[i1], 1);
  }
}

// ------------------------------------------------------------------
// 2. Scan: padded per-expert offsets + tile list (single thread; E=8)
// ------------------------------------------------------------------
__global__ void scan_kernel(const int* __restrict__ counts, int* __restrict__ offsets,
                            int* __restrict__ cursors, int* __restrict__ n_tiles,
                            int* __restrict__ tile_e, int* __restrict__ tile_s,
                            int* __restrict__ tile_r) {
  if (threadIdx.x == 0) {
    int off = 0, nt = 0;
    for (int e = 0; e < NE; ++e) {
      offsets[e] = off;
      cursors[e] = 0;
      int c = counts[e];
      for (int m0 = 0; m0 < c; m0 += BM) {
        tile_e[nt] = e;
        tile_s[nt] = off + m0;
        tile_r[nt] = (c - m0 < BM) ? (c - m0) : BM;
        ++nt;
      }
      off += ((c + BM - 1) / BM) * BM;   // padded region per expert
    }
    *n_tiles = nt;
  }
}

// ------------------------------------------------------------------
// 3. Scatter tokens into per-expert pair slots
// ------------------------------------------------------------------
__global__ void scatter_kernel(const int* __restrict__ topi, const float* __restrict__ topw,
                               const int* __restrict__ offsets, int* __restrict__ cursors,
                               int* __restrict__ ptok, float* __restrict__ pw) {
  int t = blockIdx.x * 256 + threadIdx.x;
  if (t >= T_TOK) return;
#pragma unroll
  for (int k = 0; k < 2; ++k) {
    int e = topi[t * 2 + k];
    int pos = atomicAdd(&cursors[e], 1);
    int p = offsets[e] + pos;
    ptok[p] = t;
    pw[p] = topw[t * 2 + k];
  }
}

// ------------------------------------------------------------------
// 4a. x fp32 -> bf16 (vectorized)
// ------------------------------------------------------------------
__global__ void convert_x(const float* __restrict__ x, ushort_t* __restrict__ xb) {
  size_t i = ((size_t)blockIdx.x * 256 + threadIdx.x) * 8;
  float4 a = *(const float4*)&x[i];
  float4 b = *(const float4*)&x[i + 4];
  ushort4 lo = { f2bf(a.x), f2bf(a.y), f2bf(a.z), f2bf(a.w) };
  ushort4 hi = { f2bf(b.x), f2bf(b.y), f2bf(b.z), f2bf(b.w) };
  *(ushort4*)&xb[i] = lo;
  *(ushort4*)&xb[i + 4] = hi;
}

// ------------------------------------------------------------------
// 4b. weights: fp32 [E][R][C] -> bf16 transposed [E][C][R]
// ------------------------------------------------------------------
__global__ void transpose_convert(const float* __restrict__ src, ushort_t* __restrict__ dst,
                                  int R, int C) {
  __shared__ ushort_t tile[64][72];   // padded stride breaks bank conflicts
  int e = blockIdx.z;
  src += (size_t)e * R * C;
  dst += (size_t)e * R * C;
  int c0 = blockIdx.x * 64, r0 = blockIdx.y * 64;
  int tr = threadIdx.x >> 4;          // 0..15
  int tc = (threadIdx.x & 15) << 2;   // 0,4,..,60
#pragma unroll
  for (int i = 0; i < 4; ++i) {
    int r = i * 16 + tr;
    float4 v = *(const float4*)&src[(size_t)(r0 + r) * C + c0 + tc];
    tile[tc + 0][r] = f2bf(v.x);
    tile[tc + 1][r] = f2bf(v.y);
    tile[tc + 2][r] = f2bf(v.z);
    tile[tc + 3][r] = f2bf(v.w);
  }
  __syncthreads();
#pragma unroll
  for (int i = 0; i < 4; ++i) {
    int flat = i * 256 + threadIdx.x;
    int cr = flat >> 4;               // 0..63 (C-local row of dst)
    int rg = (flat & 15) << 2;        // 0..60
    ushort4 o = { tile[cr][rg], tile[cr][rg + 1], tile[cr][rg + 2], tile[cr][rg + 3] };
    *(ushort4*)&dst[(size_t)(c0 + cr) * R + r0 + rg] = o;
  }
}

// ------------------------------------------------------------------
// 5. GEMM1: h[p][:] = relu(x[tok(p)] @ W1_e), grouped by expert tile
//    A gathered from xb via per-lane global_load_lds source.
// ------------------------------------------------------------------
__global__ __launch_bounds__(256) void gemm1_kernel(
    const ushort_t* __restrict__ xb, const ushort_t* __restrict__ w1t,
    ushort_t* __restrict__ h,
    const int* __restrict__ n_tiles, const int* __restrict__ tile_e,
    const int* __restrict__ tile_s, const int* __restrict__ tile_r,
    const int* __restrict__ ptok) {
  int tile = blockIdx.x;
  if (tile >= *n_tiles) return;
  int e = tile_e[tile], p0 = tile_s[tile], rows = tile_r[tile];
  int n0 = blockIdx.y * BN;

  __shared__ ushort_t As[BM * BK];   // [m][k]
  __shared__ ushort_t Bs[BN * BK];   // [n][k]
  int tid = threadIdx.x, wave = tid >> 6, lane = tid & 63;

  const ushort_t* a_src[4];
  const ushort_t* b_src[4];
#pragma unroll
  for (int j = 0; j < 4; ++j) {
    int r = (wave * 4 + j) * 8 + (lane >> 3);
    int c8 = (lane & 7) * 8;
    int tok = (r < rows) ? ptok[p0 + r] : 0;
    a_src[j] = xb + (size_t)tok * DM + c8;
    b_src[j] = w1t + ((size_t)e * DF + n0 + r) * DM + c8;
  }
  f32x4 acc[4][4] = {};
  int m_off = (wave >> 1) * 64, nf_off = (wave & 1) * 64;
  int frow = lane & 15, fks = (lane >> 4) * 8;

  for (int k0 = 0; k0 < DM; k0 += BK) {
#pragma unroll
    for (int j = 0; j < 4; ++j) {
      __builtin_amdgcn_global_load_lds(
          (const __attribute__((address_space(1))) void*)(a_src[j] + k0),
          (__attribute__((address_space(3))) void*)(As + (wave * 4 + j) * 512), 16, 0, 0);
      __builtin_amdgcn_global_load_lds(
          (const __attribute__((address_space(1))) void*)(b_src[j] + k0),
          (__attribute__((address_space(3))) void*)(Bs + (wave * 4 + j) * 512), 16, 0, 0);
    }
    asm volatile("s_waitcnt vmcnt(0)" ::: "memory");
    __syncthreads();
#pragma unroll
    for (int kk = 0; kk < BK; kk += 32) {
      bf16x8 af[4], bf[4];
#pragma unroll
      for (int mi = 0; mi < 4; ++mi)
        af[mi] = *(const bf16x8*)&As[(m_off + mi * 16 + frow) * BK + kk + fks];
#pragma unroll
      for (int ni = 0; ni < 4; ++ni)
        bf[ni] = *(const bf16x8*)&Bs[(nf_off + ni * 16 + frow) * BK + kk + fks];
#pragma unroll
      for (int mi = 0; mi < 4; ++mi)
#pragma unroll
        for (int ni = 0; ni < 4; ++ni)
          acc[mi][ni] = __builtin_amdgcn_mfma_f32_16x16x32_bf16(af[mi], bf[ni], acc[mi][ni], 0, 0, 0);
    }
    __syncthreads();
  }
  // epilogue: relu -> bf16 h; zero pad rows so GEMM2 reads clean data
  int col = lane & 15;
#pragma unroll
  for (int mi = 0; mi < 4; ++mi) {
#pragma unroll
    for (int r = 0; r < 4; ++r) {
      int m = m_off + mi * 16 + (lane >> 4) * 4 + r;
      bool valid = m < rows;
      size_t rowoff = (size_t)(p0 + m) * DF + n0 + nf_off;
#pragma unroll
      for (int ni = 0; ni < 4; ++ni) {
        float v = acc[mi][ni][r];
        v = valid ? (v > 0.f ? v : 0.f) : 0.f;
        h[rowoff + ni * 16 + col] = f2bf(v);
      }
    }
  }
}

// ------------------------------------------------------------------
// 6. GEMM2: out[tok(p)] += w(p) * (h[p] @ W2_e)   (atomic scatter)
// ------------------------------------------------------------------
__global__ __launch_bounds__(256) void gemm2_kernel(
    const ushort_t* __restrict__ h, const ushort_t* __restrict__ w2t,
    float* __restrict__ out,
    const int* __restrict__ n_tiles, const int* __restrict__ tile_e,
    const int* __restrict__ tile_s, const int* __restrict__ tile_r,
    const int* __restrict__ ptok, const float* __restrict__ pw) {
  int tile = blockIdx.x;
  if (tile >= *n_tiles) return;
  int e = tile_e[tile], p0 = tile_s[tile], rows = tile_r[tile];
  int n0 = blockIdx.y * BN;

  __shared__ ushort_t As[BM * BK];
  __shared__ ushort_t Bs[BN * BK];
  int tid = threadIdx.x, wave = tid >> 6, lane = tid & 63;

  const ushort_t* a_src[4];
  const ushort_t* b_src[4];
#pragma unroll
  for (int j = 0; j < 4; ++j) {
    int r = (wave * 4 + j) * 8 + (lane >> 3);
    int c8 = (lane & 7) * 8;
    a_src[j] = h + (size_t)(p0 + r) * DF + c8;            // contiguous rows, pads are zeroed
    b_src[j] = w2t + ((size_t)e * DM + n0 + r) * DF + c8;
  }
  f32x4 acc[4][4] = {};
  int m_off = (wave >> 1) * 64, nf_off = (wave & 1) * 64;
  int frow = lane & 15, fks = (lane >> 4) * 8;

  for (int k0 = 0; k0 < DF; k0 += BK) {
#pragma unroll
    for (int j = 0; j < 4; ++j) {
      __builtin_amdgcn_global_load_lds(
          (const __attribute__((address_space(1))) void*)(a_src[j] + k0),
          (__attribute__((address_space(3))) void*)(As + (wave * 4 + j) * 512), 16, 0, 0);
      __builtin_amdgcn_global_load_lds(
          (const __attribute__((address_space(1))) void*)(b_src[j] + k0),
          (__attribute__((address_space(3))) void*)(Bs + (wave * 4 + j) * 512), 16, 0, 0);
    }
    asm volatile("s_waitcnt vmcnt(0)" ::: "memory");
    __syncthreads();
#pragma unroll
    for (int kk = 0; kk < BK; kk += 32) {
      bf16x8 af[4], bf[4];
#pragma unroll
      for (int mi = 0; mi < 4; ++mi)
        af[mi] = *(const bf16x8*)&As[(m_off + mi * 16 + frow) * BK + kk + fks];
#pragma unroll
      for (int ni = 0; ni < 4; ++ni)
        bf[ni] = *(const bf16x8*)&Bs[(nf_off + ni * 16 + frow) * BK + kk + fks];
#pragma unroll
      for (int mi = 0; mi < 4; ++mi)
#pragma unroll
        for (int ni = 0; ni < 4; ++ni)
          acc[mi][ni] = __builtin_amdgcn_mfma_f32_16x16x32_bf16(af[mi], bf[ni], acc[mi][ni], 0, 0, 0);
    }
    __syncthreads();
  }
  // epilogue: weighted atomic scatter (exactly 2 adds per out element -> deterministic)
  int col = lane & 15;
#pragma unroll
  for (int mi = 0; mi < 4; ++mi) {
#pragma unroll
    for (int r = 0; r < 4; ++r) {
      int m = m_off + mi * 16 + (lane >> 4) * 4 + r;
      if (m < rows) {
        int p = p0 + m;
        int tok = ptok[p];
        float w = pw[p];
        size_t o = (size_t)tok * DM + n0 + nf_off;
#pragma unroll
        for (int ni = 0; ni < 4; ++ni)
          atomicAdd(&out[o + ni * 16 + col], w * acc[mi][ni][r]);
      }
    }
  }
}

// ------------------------------------------------------------------
extern "C" void kernel_launch(void* const* d_in, const int* in_sizes, int n_in,
                              void* d_out, int out_size, void* d_ws, size_t ws_size,
                              hipStream_t stream) {
  const float* x  = (const float*)d_in[0];   // [2,2048,1024]
  const float* gw = (const float*)d_in[1];   // [1024,8]
  const float* w1 = (const float*)d_in[2];   // [8,1024,4096]
  const float* w2 = (const float*)d_in[3];   // [8,4096,1024]
  float* out = (float*)d_out;                // [4096,1024]
  char* ws = (char*)d_ws;
  if (ws_size < WS_NEEDED) return;           // visible failure if ws too small

  ushort_t* w1t = (ushort_t*)(ws + W1T_OFF);
  ushort_t* w2t = (ushort_t*)(ws + W2T_OFF);
  ushort_t* xb  = (ushort_t*)(ws + XB_OFF);
  ushort_t* h   = (ushort_t*)(ws + H_OFF);
  char* rt = ws + RT_OFF;
  int*   counts  = (int*)(rt + RO_COUNTS);
  int*   offsets = (int*)(rt + RO_OFFSETS);
  int*   cursors = (int*)(rt + RO_CURSORS);
  int*   n_tiles = (int*)(rt + RO_NTILES);
  int*   tile_e  = (int*)(rt + RO_TILE_E);
  int*   tile_s  = (int*)(rt + RO_TILE_S);
  int*   tile_r  = (int*)(rt + RO_TILE_R);
  int*   ptok    = (int*)(rt + RO_PTOK);
  float* pw      = (float*)(rt + RO_PW);
  int*   topi    = (int*)(rt + RO_TOPI);
  float* topw    = (float*)(rt + RO_TOPW);

  hipMemsetAsync(out, 0, (size_t)T_TOK * DM * sizeof(float), stream);
  hipMemsetAsync(rt, 0, 128, stream);   // counts/offsets/cursors/n_tiles

  hipLaunchKernelGGL(gate_kernel, dim3(T_TOK / 4), dim3(256), 0, stream, x, gw, counts, topi, topw);
  hipLaunchKernelGGL(scan_kernel, dim3(1), dim3(64), 0, stream,
                     counts, offsets, cursors, n_tiles, tile_e, tile_s, tile_r);
  hipLaunchKernelGGL(scatter_kernel, dim3(T_TOK / 256), dim3(256), 0, stream,
                     topi, topw, offsets, cursors, ptok, pw);
  hipLaunchKernelGGL(convert_x, dim3((T_TOK * DM) / (256 * 8)), dim3(256), 0, stream, x, xb);
  hipLaunchKernelGGL(transpose_convert, dim3(DF / 64, DM / 64, NE), dim3(256), 0, stream,
                     w1, w1t, DM, DF);
  hipLaunchKernelGGL(transpose_convert, dim3(DM / 64, DF / 64, NE), dim3(256), 0, stream,
                     w2, w2t, DF, DM);
  hipLaunchKernelGGL(gemm1_kernel, dim3(MAX_TILES, DF / BN), dim3(256), 0, stream,
                     xb, w1t, h, n_tiles, tile_e, tile_s, tile_r, ptok);
  hipLaunchKernelGGL(gemm2_kernel, dim3(MAX_TILES, DM / BN), dim3(256), 0, stream,
                     h, w2t, out, n_tiles, tile_e, tile_s, tile_r, ptok, pw);
}